// Round 5
// baseline (1045.067 us; speedup 1.0000x reference)
//
#include <hip/hip_runtime.h>
#include <math.h>

// GIN: N=100000 nodes, E=1600000 edges, F=D=64, L=3 layers, C=10 classes.
// R5: (1) neighbor gather reads a bf16 shadow of h (halves the compulsory
// 8-XCD L2 streaming floor, was 196MB/agg); shadow written for free inside
// k_head_init (x) and k_bn_head (h). (2) launch collapse 29->18: agg fused
// into GEMM1 A-staging; k_bnfin folded into consumer prologues (stats are
// complete at kernel boundary); node-scan pass2 inlined into pass3;
// log-softmax fused into last bn_head (which also skips h stores).

#define BN_EPS 1e-5f
#define SCAN_CHUNK 512  // elements per block in node-level scan (N<=131072)
#define NBKT 256        // dst buckets (dst>>9 -> <=196 used)
#define PCHUNK 8192     // edges per partition block

__device__ __forceinline__ float bf2f(unsigned short u) {
  return __uint_as_float(((unsigned int)u) << 16);
}
__device__ __forceinline__ unsigned short f2bf(float x) {  // RNE
  unsigned int b = __float_as_uint(x);
  return (unsigned short)((b + 0x7FFFu + ((b >> 16) & 1u)) >> 16);
}

// ---------- CSR build ----------

__global__ __launch_bounds__(256) void k_buckethist(const int* __restrict__ dst,
                                                    int* __restrict__ bcnt, int E) {
  __shared__ int lh[NBKT];
  lh[threadIdx.x] = 0;
  __syncthreads();
  for (int e = blockIdx.x * 256 + threadIdx.x; e < E; e += gridDim.x * 256)
    atomicAdd(&lh[dst[e] >> 9], 1);
  __syncthreads();
  int c = lh[threadIdx.x];
  if (c) atomicAdd(&bcnt[threadIdx.x], c);
}

__global__ __launch_bounds__(256) void k_scanblock(const int* __restrict__ sums,
                                                   int* __restrict__ excl, int nblk) {
  __shared__ int ts[256];
  int t = threadIdx.x;
  int v = (t < nblk) ? sums[t] : 0;
  ts[t] = v;
  __syncthreads();
  for (int o = 1; o < 256; o <<= 1) {
    int add = (t >= o) ? ts[t - o] : 0;
    __syncthreads();
    ts[t] += add;
    __syncthreads();
  }
  excl[t] = ts[t] - v;
}

__global__ __launch_bounds__(256) void k_partition(const int* __restrict__ src,
                                                   const int* __restrict__ dst,
                                                   int* __restrict__ bcur,
                                                   int2* __restrict__ ep, int E) {
  __shared__ int lh[NBKT];
  __shared__ int lbase[NBKT];
  __shared__ int lcur[NBKT];
  int base = blockIdx.x * PCHUNK;
  int end = min(base + PCHUNK, E);
  lh[threadIdx.x] = 0;
  lcur[threadIdx.x] = 0;
  __syncthreads();
  for (int e = base + threadIdx.x; e < end; e += 256) atomicAdd(&lh[dst[e] >> 9], 1);
  __syncthreads();
  int c = lh[threadIdx.x];
  lbase[threadIdx.x] = c ? atomicAdd(&bcur[threadIdx.x], c) : 0;
  __syncthreads();
  for (int e = base + threadIdx.x; e < end; e += 256) {
    int d = dst[e];
    int b = d >> 9;
    int r = atomicAdd(&lcur[b], 1);
    ep[lbase[b] + r] = make_int2(src[e], d);
  }
}

__global__ void k_hist2(const int2* __restrict__ ep, int* __restrict__ counts, int E) {
  int e = blockIdx.x * blockDim.x + threadIdx.x;
  if (e < E) atomicAdd(&counts[ep[e].y], 1);
}

__global__ __launch_bounds__(256) void k_blocksum(const int* __restrict__ counts,
                                                  int* __restrict__ blocksums, int N) {
  __shared__ int ls[256];
  int t = threadIdx.x;
  int base = blockIdx.x * SCAN_CHUNK;
  int i0 = base + 2 * t, i1 = i0 + 1;
  int c0 = (i0 < N) ? counts[i0] : 0;
  int c1 = (i1 < N) ? counts[i1] : 0;
  ls[t] = c0 + c1;
  __syncthreads();
  for (int o = 128; o > 0; o >>= 1) {
    if (t < o) ls[t] += ls[t + o];
    __syncthreads();
  }
  if (t == 0) blocksums[blockIdx.x] = ls[0];
}

// node-scan pass 3 with pass-2 inlined (each block re-scans the block sums)
__global__ __launch_bounds__(256) void k_scanfinal2(
    const int* __restrict__ counts, const int* __restrict__ blocksums, int nscan,
    int* __restrict__ offs, int* __restrict__ cursor, int N) {
  __shared__ int bs[256];
  __shared__ int ts[256];
  int t = threadIdx.x;
  int bv = (t < nscan) ? blocksums[t] : 0;
  bs[t] = bv;
  __syncthreads();
  for (int o = 1; o < 256; o <<= 1) {
    int add = (t >= o) ? bs[t - o] : 0;
    __syncthreads();
    bs[t] += add;
    __syncthreads();
  }
  if (t < nscan) bs[t] -= bv;  // exclusive
  __syncthreads();
  int myoff = bs[blockIdx.x];
  int base = blockIdx.x * SCAN_CHUNK;
  int i0 = base + 2 * t, i1 = i0 + 1;
  int c0 = (i0 < N) ? counts[i0] : 0;
  int c1 = (i1 < N) ? counts[i1] : 0;
  int s = c0 + c1;
  ts[t] = s;
  __syncthreads();
  for (int o = 1; o < 256; o <<= 1) {
    int add = (t >= o) ? ts[t - o] : 0;
    __syncthreads();
    ts[t] += add;
    __syncthreads();
  }
  int excl = ts[t] - s + myoff;
  if (i0 < N) {
    offs[i0] = excl;
    cursor[i0] = excl;
  }
  if (i1 < N) {
    offs[i1] = excl + c0;
    cursor[i1] = excl + c0;
  }
  if (i0 == N - 1) offs[N] = excl + c0;
  else if (i1 == N - 1) offs[N] = excl + c0 + c1;
}

__global__ void k_scatter2(const int2* __restrict__ ep, int* __restrict__ cursor,
                           int* __restrict__ csr, int E) {
  int e = blockIdx.x * blockDim.x + threadIdx.x;
  if (e < E) {
    int2 p = ep[e];
    int pos = atomicAdd(&cursor[p.y], 1);
    csr[pos] = p.x;
  }
}

// ---------- compute ----------

// Unified LDS-tiled GEMM, 128 rows/block, 4x8 thread tile.
//  agg=1: A row = vin[row] (fp32 self) + sum of bf16 neighbor gathers.
//  dobn=1: AB computed in prologue from stats_in/gv/bev; BN+ReLU on A staging.
// Epilogue: column sum/sumsq -> atomicAdd stats_out[128].
__global__ __launch_bounds__(256) void k_gemm2(
    const float* __restrict__ vin, float* __restrict__ zout,
    const float* __restrict__ W,
    const float* __restrict__ stats_in, const float* __restrict__ gv,
    const float* __restrict__ bev, int dobn,
    float* __restrict__ stats_out,
    const int* __restrict__ offs, const int* __restrict__ csr,
    const unsigned short* __restrict__ h16, int agg, int N) {
  __shared__ float As[128 * 68];
  __shared__ float Ws[64 * 68];
  __shared__ float ABs[128];
  int tid = threadIdx.x;
  int n0 = blockIdx.x * 128;
  if (dobn) {
    if (tid < 64) {
      float inv_n = 1.f / (float)N;
      float mu = stats_in[tid] * inv_n;
      float var = stats_in[64 + tid] * inv_n - mu * mu;
      float A = rsqrtf(var + BN_EPS) * gv[tid];
      ABs[tid] = A;
      ABs[64 + tid] = bev[tid] - mu * A;
    }
    __syncthreads();
  }
#pragma unroll
  for (int i = 0; i < 4; i++) {  // stage W (64x64)
    int g = tid + i * 256;
    int r = g >> 4, q = g & 15;
    float4 t = *(const float4*)(W + r * 64 + 4 * q);
    int base = r * 68 + 4 * q;
    Ws[base] = t.x; Ws[base + 1] = t.y; Ws[base + 2] = t.z; Ws[base + 3] = t.w;
  }
  if (agg) {
    int wv = tid >> 6, lane = tid & 63;
    for (int r = wv * 32; r < wv * 32 + 32; r++) {
      int rn = n0 + r;
      float acc = 0.f;
      if (rn < N) {
        acc = vin[(size_t)rn * 64 + lane];
        int e0 = offs[rn], e1 = offs[rn + 1];
        int e = e0;
        for (; e + 8 <= e1; e += 8) {
          int s0 = csr[e], s1 = csr[e + 1], s2 = csr[e + 2], s3 = csr[e + 3];
          int s4 = csr[e + 4], s5 = csr[e + 5], s6 = csr[e + 6], s7 = csr[e + 7];
          float a0 = bf2f(h16[(size_t)s0 * 64 + lane]);
          float a1 = bf2f(h16[(size_t)s1 * 64 + lane]);
          float a2 = bf2f(h16[(size_t)s2 * 64 + lane]);
          float a3 = bf2f(h16[(size_t)s3 * 64 + lane]);
          float a4 = bf2f(h16[(size_t)s4 * 64 + lane]);
          float a5 = bf2f(h16[(size_t)s5 * 64 + lane]);
          float a6 = bf2f(h16[(size_t)s6 * 64 + lane]);
          float a7 = bf2f(h16[(size_t)s7 * 64 + lane]);
          acc += ((a0 + a1) + (a2 + a3)) + ((a4 + a5) + (a6 + a7));
        }
        for (; e < e1; e++) acc += bf2f(h16[(size_t)csr[e] * 64 + lane]);
      }
      As[r * 68 + lane] = acc;
    }
  } else {
#pragma unroll
    for (int i = 0; i < 8; i++) {  // stage A (128x64), optional BN+ReLU
      int g = tid + i * 256;
      int r = g >> 4, q = g & 15;
      int rn = n0 + r;
      float4 t = make_float4(0.f, 0.f, 0.f, 0.f);
      if (rn < N) t = *(const float4*)(vin + (size_t)rn * 64 + 4 * q);
      if (dobn) {
        float4 a = *(const float4*)(ABs + 4 * q);
        float4 b = *(const float4*)(ABs + 64 + 4 * q);
        t.x = fmaxf(t.x * a.x + b.x, 0.f);
        t.y = fmaxf(t.y * a.y + b.y, 0.f);
        t.z = fmaxf(t.z * a.z + b.z, 0.f);
        t.w = fmaxf(t.w * a.w + b.w, 0.f);
      }
      int base = r * 68 + 4 * q;
      As[base] = t.x; As[base + 1] = t.y; As[base + 2] = t.z; As[base + 3] = t.w;
    }
  }
  __syncthreads();
  int tr = tid >> 3, tc = tid & 7;
  int ra = tr * 4;
  float acc[4][8];
#pragma unroll
  for (int i = 0; i < 4; i++)
#pragma unroll
    for (int j = 0; j < 8; j++) acc[i][j] = 0.f;
#pragma unroll 4
  for (int k = 0; k < 64; k++) {
    float av[4];
#pragma unroll
    for (int i = 0; i < 4; i++) av[i] = As[(ra + i) * 68 + k];
    const float* wk = &Ws[k * 68 + tc * 8];
    float4 w0 = *(const float4*)wk;
    float4 w1 = *(const float4*)(wk + 4);
    float wv[8] = {w0.x, w0.y, w0.z, w0.w, w1.x, w1.y, w1.z, w1.w};
#pragma unroll
    for (int i = 0; i < 4; i++)
#pragma unroll
      for (int j = 0; j < 8; j++) acc[i][j] += av[i] * wv[j];
  }
#pragma unroll
  for (int i = 0; i < 4; i++) {
    int rn = n0 + ra + i;
    if (rn < N) {
      float* zr = zout + (size_t)rn * 64 + tc * 8;
      *(float4*)zr = make_float4(acc[i][0], acc[i][1], acc[i][2], acc[i][3]);
      *(float4*)(zr + 4) = make_float4(acc[i][4], acc[i][5], acc[i][6], acc[i][7]);
    }
  }
  float cs[8], cq[8];
#pragma unroll
  for (int j = 0; j < 8; j++) {
    float s = 0.f, q = 0.f;
#pragma unroll
    for (int i = 0; i < 4; i++) {
      s += acc[i][j];
      q += acc[i][j] * acc[i][j];
    }
    cs[j] = s;
    cq[j] = q;
  }
#pragma unroll
  for (int m = 8; m <= 32; m <<= 1) {
#pragma unroll
    for (int j = 0; j < 8; j++) {
      cs[j] += __shfl_xor(cs[j], m);
      cq[j] += __shfl_xor(cq[j], m);
    }
  }
  __syncthreads();  // Ws reusable
  int w = tid >> 6;
  if ((tid & 63) < 8) {
    int c = tc * 8;
#pragma unroll
    for (int j = 0; j < 8; j++) {
      Ws[w * 128 + c + j] = cs[j];
      Ws[w * 128 + 64 + c + j] = cq[j];
    }
  }
  __syncthreads();
  if (tid < 64) {
    float a = Ws[tid] + Ws[128 + tid] + Ws[256 + tid] + Ws[384 + tid];
    float b = Ws[64 + tid] + Ws[192 + tid] + Ws[320 + tid] + Ws[448 + tid];
    atomicAdd(&stats_out[tid], a);
    atomicAdd(&stats_out[64 + tid], b);
  }
}

// logits[n] = x[n] @ fcW0 + sum_l fcb[l]; also emits x16 (bf16 shadow of x)
__global__ __launch_bounds__(256) void k_head_init(
    const float* __restrict__ x, const float* __restrict__ fcW0,
    const float* __restrict__ fcb, float* __restrict__ logits,
    unsigned short* __restrict__ x16, int N) {
  __shared__ float vs[256 * 17];
  int tid = threadIdx.x;
  int n0 = blockIdx.x * 256;
  int n = n0 + tid;
  float acc[10];
#pragma unroll
  for (int c = 0; c < 10; c++) acc[c] = 0.f;
#pragma unroll 1
  for (int fb = 0; fb < 64; fb += 16) {
    __syncthreads();
#pragma unroll
    for (int g = 0; g < 4; g++) {
      int r = g * 64 + (tid >> 2);
      int q = tid & 3;
      int rn = n0 + r;
      float4 t = make_float4(0.f, 0.f, 0.f, 0.f);
      if (rn < N) {
        t = *(const float4*)(x + (size_t)rn * 64 + fb + 4 * q);
        *(ushort4*)(x16 + (size_t)rn * 64 + fb + 4 * q) =
            make_ushort4(f2bf(t.x), f2bf(t.y), f2bf(t.z), f2bf(t.w));
      }
      int base = r * 17 + 4 * q;
      vs[base] = t.x;
      vs[base + 1] = t.y;
      vs[base + 2] = t.z;
      vs[base + 3] = t.w;
    }
    __syncthreads();
    for (int fc = 0; fc < 16; fc++) {
      int f = fb + fc;
      float vf = vs[tid * 17 + fc];
      const float* wr = fcW0 + f * 10;
#pragma unroll
      for (int c = 0; c < 10; c++) acc[c] += vf * wr[c];
    }
  }
  if (n < N) {
    float* lr = logits + (size_t)n * 10;
#pragma unroll
    for (int c = 0; c < 10; c++)
      lr[c] = acc[c] + (fcb[c] + fcb[10 + c] + fcb[20 + c] + fcb[30 + c]);
  }
}

// h = relu(z*A+B) with AB from stats prologue; store h + h16; logits += h@fcWl.
// dofinal: skip h/h16 stores, finish logits and write log_softmax to out.
__global__ __launch_bounds__(256) void k_bn_head(
    const float* __restrict__ z,
    const float* __restrict__ stats_in, const float* __restrict__ gv,
    const float* __restrict__ bev,
    float* __restrict__ hout, unsigned short* __restrict__ h16out,
    const float* __restrict__ fcWl, float* __restrict__ logits,
    float* __restrict__ out, int dofinal, int N) {
  __shared__ float vs[256 * 17];
  __shared__ float ABs[128];
  int tid = threadIdx.x;
  if (tid < 64) {
    float inv_n = 1.f / (float)N;
    float mu = stats_in[tid] * inv_n;
    float var = stats_in[64 + tid] * inv_n - mu * mu;
    float A = rsqrtf(var + BN_EPS) * gv[tid];
    ABs[tid] = A;
    ABs[64 + tid] = bev[tid] - mu * A;
  }
  int n0 = blockIdx.x * 256;
  int n = n0 + tid;
  float acc[10];
#pragma unroll
  for (int c = 0; c < 10; c++) acc[c] = 0.f;
#pragma unroll 1
  for (int fb = 0; fb < 64; fb += 16) {
    __syncthreads();
#pragma unroll
    for (int g = 0; g < 4; g++) {
      int r = g * 64 + (tid >> 2);
      int q = tid & 3;
      int rn = n0 + r;
      float4 t = (rn < N) ? *(const float4*)(z + (size_t)rn * 64 + fb + 4 * q)
                          : make_float4(0.f, 0.f, 0.f, 0.f);
      int base = r * 17 + 4 * q;
      vs[base] = t.x;
      vs[base + 1] = t.y;
      vs[base + 2] = t.z;
      vs[base + 3] = t.w;
    }
    __syncthreads();
    float tl[16];
#pragma unroll
    for (int fc = 0; fc < 16; fc++) {
      int f = fb + fc;
      float val = vs[tid * 17 + fc] * ABs[f] + ABs[64 + f];
      tl[fc] = fmaxf(val, 0.f);
      const float* wr = fcWl + f * 10;
#pragma unroll
      for (int c = 0; c < 10; c++) acc[c] += tl[fc] * wr[c];
    }
    if (!dofinal) {
      __syncthreads();
#pragma unroll
      for (int fc = 0; fc < 16; fc++) vs[tid * 17 + fc] = tl[fc];
      __syncthreads();
#pragma unroll
      for (int g = 0; g < 4; g++) {  // coalesced h + h16 store via LDS bounce
        int r = g * 64 + (tid >> 2);
        int q = tid & 3;
        int rn = n0 + r;
        if (rn < N) {
          int base = r * 17 + 4 * q;
          float4 t = make_float4(vs[base], vs[base + 1], vs[base + 2], vs[base + 3]);
          *(float4*)(hout + (size_t)rn * 64 + fb + 4 * q) = t;
          *(ushort4*)(h16out + (size_t)rn * 64 + fb + 4 * q) =
              make_ushort4(f2bf(t.x), f2bf(t.y), f2bf(t.z), f2bf(t.w));
        }
      }
    }
  }
  if (n < N) {
    float* lr = logits + (size_t)n * 10;
    if (!dofinal) {
#pragma unroll
      for (int c = 0; c < 10; c++) lr[c] += acc[c];
    } else {
      float v[10];
      float m = -INFINITY;
#pragma unroll
      for (int c = 0; c < 10; c++) {
        v[c] = lr[c] + acc[c];
        m = fmaxf(m, v[c]);
      }
      float s = 0.f;
#pragma unroll
      for (int c = 0; c < 10; c++) s += expf(v[c] - m);
      float l = logf(s) + m;
      float* orow = out + (size_t)n * 10;
#pragma unroll
      for (int c = 0; c < 10; c++) orow[c] = v[c] - l;
    }
  }
}

extern "C" void kernel_launch(void* const* d_in, const int* in_sizes, int n_in,
                              void* d_out, int out_size, void* d_ws, size_t ws_size,
                              hipStream_t stream) {
  const float* x = (const float*)d_in[0];
  const int* ei = (const int*)d_in[1];
  const float* W1 = (const float*)d_in[2];
  const float* g1 = (const float*)d_in[4];
  const float* be1 = (const float*)d_in[5];
  const float* W2 = (const float*)d_in[6];
  const float* gbn = (const float*)d_in[8];
  const float* bbn = (const float*)d_in[9];
  const float* fcW = (const float*)d_in[10];
  const float* fcb = (const float*)d_in[11];
  float* out = (float*)d_out;

  const int N = in_sizes[0] / 64;
  const int E = in_sizes[1] / 2;
  const int* src = ei;
  const int* dst = ei + E;

  char* ws = (char*)d_ws;
  size_t off = 0;
  auto alloc = [&](size_t bytes) -> void* {
    void* p = ws + off;
    off = (off + bytes + 255) & ~(size_t)255;
    return p;
  };
  // zero-initialized region (single memset): counts + bcnt + stats
  int* counts = (int*)alloc((size_t)N * 4);
  int* bcnt = (int*)alloc(NBKT * 4);
  float* stats = (float*)alloc(6 * 128 * 4);
  size_t zspan = off;  // memset [ws, ws+zspan)
  int* bcur = (int*)alloc(NBKT * 4);
  int* offs = (int*)alloc((size_t)(N + 1) * 4);
  int* cursor = (int*)alloc((size_t)N * 4);
  int* csr = (int*)alloc((size_t)E * 4);
  float* hbuf = (float*)alloc((size_t)N * 64 * 4);
  float* zbuf = (float*)alloc((size_t)N * 64 * 4);
  float* logits = (float*)alloc((size_t)N * 10 * 4);
  int* blocksums = (int*)alloc(256 * 4);
  unsigned short* x16 = (unsigned short*)alloc((size_t)N * 64 * 2);
  unsigned short* h16 = (unsigned short*)alloc((size_t)N * 64 * 2);
  int2* ep = (int2*)zbuf;  // alias: ep dead before first k_gemm2 writes zbuf
  (void)ws_size;
  (void)n_in;
  (void)out_size;

  hipMemsetAsync(ws, 0, zspan, stream);
  int eb = (E + 255) / 256;
  int nb = (N + 255) / 256;
  int gb = (N + 127) / 128;
  int nscan = (N + SCAN_CHUNK - 1) / SCAN_CHUNK;  // <=256
  int nparts = (E + PCHUNK - 1) / PCHUNK;
  k_buckethist<<<512, 256, 0, stream>>>(dst, bcnt, E);
  k_scanblock<<<1, 256, 0, stream>>>(bcnt, bcur, NBKT);
  k_partition<<<nparts, 256, 0, stream>>>(src, dst, bcur, ep, E);
  k_hist2<<<eb, 256, 0, stream>>>(ep, counts, E);
  k_blocksum<<<nscan, 256, 0, stream>>>(counts, blocksums, N);
  k_scanfinal2<<<nscan, 256, 0, stream>>>(counts, blocksums, nscan, offs, cursor, N);
  k_scatter2<<<eb, 256, 0, stream>>>(ep, cursor, csr, E);
  k_head_init<<<nb, 256, 0, stream>>>(x, fcW, fcb, logits, x16, N);

  const float* hin = x;
  const unsigned short* hin16 = x16;
  for (int l = 0; l < 3; l++) {
    float* st1 = stats + (2 * l) * 128;
    float* st2 = stats + (2 * l + 1) * 128;
    // GEMM1 with fused aggregation (agg=1, dobn=0)
    k_gemm2<<<gb, 256, 0, stream>>>(hin, zbuf, W1 + l * 4096, nullptr, nullptr,
                                    nullptr, 0, st1, offs, csr, hin16, 1, N);
    // GEMM2 with fused BN-finalize prologue (dobn=1, in-place on zbuf)
    k_gemm2<<<gb, 256, 0, stream>>>(zbuf, zbuf, W2 + l * 4096, st1, g1 + l * 64,
                                    be1 + l * 64, 1, st2, nullptr, nullptr,
                                    nullptr, 0, N);
    int dofinal = (l == 2) ? 1 : 0;
    k_bn_head<<<nb, 256, 0, stream>>>(zbuf, st2, gbn + l * 64, bbn + l * 64, hbuf,
                                      h16, fcW + (l + 1) * 640, logits, out,
                                      dofinal, N);
    hin = hbuf;
    hin16 = h16;
  }
}

// Round 6
// 661.050 us; speedup vs baseline: 1.5809x; 1.5809x over previous
//
#include <hip/hip_runtime.h>
#include <math.h>

// GIN: N=100000 nodes, E=1600000 edges, F=D=64, L=3 layers, C=10 classes.
// R6: un-fuse agg from GEMM1 (R5 fusion collapsed gather latency hiding:
// 52KB-LDS blocks -> 3/CU vs standalone k_agg's 68% occupancy; 214us vs
// 59+15us). Keep R5's wins: bf16 neighbor gather (halved streaming floor),
// bnfin folded into consumer prologues, inlined scan pass2, final
// log-softmax fused into last bn_head.

#define BN_EPS 1e-5f
#define SCAN_CHUNK 512  // elements per block in node-level scan (N<=131072)
#define NBKT 256        // dst buckets (dst>>9 -> <=196 used)
#define PCHUNK 8192     // edges per partition block

__device__ __forceinline__ float bf2f(unsigned short u) {
  return __uint_as_float(((unsigned int)u) << 16);
}
__device__ __forceinline__ unsigned short f2bf(float x) {  // RNE
  unsigned int b = __float_as_uint(x);
  return (unsigned short)((b + 0x7FFFu + ((b >> 16) & 1u)) >> 16);
}

// ---------- CSR build ----------

__global__ __launch_bounds__(256) void k_buckethist(const int* __restrict__ dst,
                                                    int* __restrict__ bcnt, int E) {
  __shared__ int lh[NBKT];
  lh[threadIdx.x] = 0;
  __syncthreads();
  for (int e = blockIdx.x * 256 + threadIdx.x; e < E; e += gridDim.x * 256)
    atomicAdd(&lh[dst[e] >> 9], 1);
  __syncthreads();
  int c = lh[threadIdx.x];
  if (c) atomicAdd(&bcnt[threadIdx.x], c);
}

__global__ __launch_bounds__(256) void k_scanblock(const int* __restrict__ sums,
                                                   int* __restrict__ excl, int nblk) {
  __shared__ int ts[256];
  int t = threadIdx.x;
  int v = (t < nblk) ? sums[t] : 0;
  ts[t] = v;
  __syncthreads();
  for (int o = 1; o < 256; o <<= 1) {
    int add = (t >= o) ? ts[t - o] : 0;
    __syncthreads();
    ts[t] += add;
    __syncthreads();
  }
  excl[t] = ts[t] - v;
}

__global__ __launch_bounds__(256) void k_partition(const int* __restrict__ src,
                                                   const int* __restrict__ dst,
                                                   int* __restrict__ bcur,
                                                   int2* __restrict__ ep, int E) {
  __shared__ int lh[NBKT];
  __shared__ int lbase[NBKT];
  __shared__ int lcur[NBKT];
  int base = blockIdx.x * PCHUNK;
  int end = min(base + PCHUNK, E);
  lh[threadIdx.x] = 0;
  lcur[threadIdx.x] = 0;
  __syncthreads();
  for (int e = base + threadIdx.x; e < end; e += 256) atomicAdd(&lh[dst[e] >> 9], 1);
  __syncthreads();
  int c = lh[threadIdx.x];
  lbase[threadIdx.x] = c ? atomicAdd(&bcur[threadIdx.x], c) : 0;
  __syncthreads();
  for (int e = base + threadIdx.x; e < end; e += 256) {
    int d = dst[e];
    int b = d >> 9;
    int r = atomicAdd(&lcur[b], 1);
    ep[lbase[b] + r] = make_int2(src[e], d);
  }
}

__global__ void k_hist2(const int2* __restrict__ ep, int* __restrict__ counts, int E) {
  int e = blockIdx.x * blockDim.x + threadIdx.x;
  if (e < E) atomicAdd(&counts[ep[e].y], 1);
}

__global__ __launch_bounds__(256) void k_blocksum(const int* __restrict__ counts,
                                                  int* __restrict__ blocksums, int N) {
  __shared__ int ls[256];
  int t = threadIdx.x;
  int base = blockIdx.x * SCAN_CHUNK;
  int i0 = base + 2 * t, i1 = i0 + 1;
  int c0 = (i0 < N) ? counts[i0] : 0;
  int c1 = (i1 < N) ? counts[i1] : 0;
  ls[t] = c0 + c1;
  __syncthreads();
  for (int o = 128; o > 0; o >>= 1) {
    if (t < o) ls[t] += ls[t + o];
    __syncthreads();
  }
  if (t == 0) blocksums[blockIdx.x] = ls[0];
}

// node-scan pass 3 with pass-2 inlined (each block re-scans the block sums)
__global__ __launch_bounds__(256) void k_scanfinal2(
    const int* __restrict__ counts, const int* __restrict__ blocksums, int nscan,
    int* __restrict__ offs, int* __restrict__ cursor, int N) {
  __shared__ int bs[256];
  __shared__ int ts[256];
  int t = threadIdx.x;
  int bv = (t < nscan) ? blocksums[t] : 0;
  bs[t] = bv;
  __syncthreads();
  for (int o = 1; o < 256; o <<= 1) {
    int add = (t >= o) ? bs[t - o] : 0;
    __syncthreads();
    bs[t] += add;
    __syncthreads();
  }
  if (t < nscan) bs[t] -= bv;  // exclusive
  __syncthreads();
  int myoff = bs[blockIdx.x];
  int base = blockIdx.x * SCAN_CHUNK;
  int i0 = base + 2 * t, i1 = i0 + 1;
  int c0 = (i0 < N) ? counts[i0] : 0;
  int c1 = (i1 < N) ? counts[i1] : 0;
  int s = c0 + c1;
  ts[t] = s;
  __syncthreads();
  for (int o = 1; o < 256; o <<= 1) {
    int add = (t >= o) ? ts[t - o] : 0;
    __syncthreads();
    ts[t] += add;
    __syncthreads();
  }
  int excl = ts[t] - s + myoff;
  if (i0 < N) {
    offs[i0] = excl;
    cursor[i0] = excl;
  }
  if (i1 < N) {
    offs[i1] = excl + c0;
    cursor[i1] = excl + c0;
  }
  if (i0 == N - 1) offs[N] = excl + c0;
  else if (i1 == N - 1) offs[N] = excl + c0 + c1;
}

__global__ void k_scatter2(const int2* __restrict__ ep, int* __restrict__ cursor,
                           int* __restrict__ csr, int E) {
  int e = blockIdx.x * blockDim.x + threadIdx.x;
  if (e < E) {
    int2 p = ep[e];
    int pos = atomicAdd(&cursor[p.y], 1);
    csr[pos] = p.x;
  }
}

// ---------- compute ----------

// wave-per-node aggregation: v[n] = h[n] (fp32) + sum_{e} bf16(h[src_e])
__global__ __launch_bounds__(256) void k_agg(
    const float* __restrict__ h, const unsigned short* __restrict__ h16,
    const int* __restrict__ offs, const int* __restrict__ csr,
    float* __restrict__ vout, int N) {
  int gid = blockIdx.x * blockDim.x + threadIdx.x;
  int wid = __builtin_amdgcn_readfirstlane(gid >> 6);  // node id, wave-uniform
  int lane = threadIdx.x & 63;
  if (wid >= N) return;
  int e0 = offs[wid];
  int e1 = offs[wid + 1];
  float acc = h[(size_t)wid * 64 + lane];
  int e = e0;
  for (; e + 8 <= e1; e += 8) {  // 8 gathers in flight
    int s0 = csr[e], s1 = csr[e + 1], s2 = csr[e + 2], s3 = csr[e + 3];
    int s4 = csr[e + 4], s5 = csr[e + 5], s6 = csr[e + 6], s7 = csr[e + 7];
    float a0 = bf2f(h16[(size_t)s0 * 64 + lane]);
    float a1 = bf2f(h16[(size_t)s1 * 64 + lane]);
    float a2 = bf2f(h16[(size_t)s2 * 64 + lane]);
    float a3 = bf2f(h16[(size_t)s3 * 64 + lane]);
    float a4 = bf2f(h16[(size_t)s4 * 64 + lane]);
    float a5 = bf2f(h16[(size_t)s5 * 64 + lane]);
    float a6 = bf2f(h16[(size_t)s6 * 64 + lane]);
    float a7 = bf2f(h16[(size_t)s7 * 64 + lane]);
    acc += ((a0 + a1) + (a2 + a3)) + ((a4 + a5) + (a6 + a7));
  }
  for (; e < e1; e++) acc += bf2f(h16[(size_t)csr[e] * 64 + lane]);
  vout[(size_t)wid * 64 + lane] = acc;
}

// LDS-tiled GEMM, 128 rows/block, 4x8 thread tile.
//  dobn=1: AB computed in prologue from stats_in/gv/bev; BN+ReLU on A staging.
// Epilogue: column sum/sumsq -> atomicAdd stats_out[128]. In-place safe.
__global__ __launch_bounds__(256) void k_gemm2(
    const float* __restrict__ vin, float* __restrict__ zout,
    const float* __restrict__ W,
    const float* __restrict__ stats_in, const float* __restrict__ gv,
    const float* __restrict__ bev, int dobn,
    float* __restrict__ stats_out, int N) {
  __shared__ float As[128 * 68];
  __shared__ float Ws[64 * 68];
  __shared__ float ABs[128];
  int tid = threadIdx.x;
  int n0 = blockIdx.x * 128;
  if (dobn) {
    if (tid < 64) {
      float inv_n = 1.f / (float)N;
      float mu = stats_in[tid] * inv_n;
      float var = stats_in[64 + tid] * inv_n - mu * mu;
      float A = rsqrtf(var + BN_EPS) * gv[tid];
      ABs[tid] = A;
      ABs[64 + tid] = bev[tid] - mu * A;
    }
    __syncthreads();
  }
#pragma unroll
  for (int i = 0; i < 4; i++) {  // stage W (64x64)
    int g = tid + i * 256;
    int r = g >> 4, q = g & 15;
    float4 t = *(const float4*)(W + r * 64 + 4 * q);
    int base = r * 68 + 4 * q;
    Ws[base] = t.x; Ws[base + 1] = t.y; Ws[base + 2] = t.z; Ws[base + 3] = t.w;
  }
#pragma unroll
  for (int i = 0; i < 8; i++) {  // stage A (128x64), optional BN+ReLU
    int g = tid + i * 256;
    int r = g >> 4, q = g & 15;
    int rn = n0 + r;
    float4 t = make_float4(0.f, 0.f, 0.f, 0.f);
    if (rn < N) t = *(const float4*)(vin + (size_t)rn * 64 + 4 * q);
    if (dobn) {
      float4 a = *(const float4*)(ABs + 4 * q);
      float4 b = *(const float4*)(ABs + 64 + 4 * q);
      t.x = fmaxf(t.x * a.x + b.x, 0.f);
      t.y = fmaxf(t.y * a.y + b.y, 0.f);
      t.z = fmaxf(t.z * a.z + b.z, 0.f);
      t.w = fmaxf(t.w * a.w + b.w, 0.f);
    }
    int base = r * 68 + 4 * q;
    As[base] = t.x; As[base + 1] = t.y; As[base + 2] = t.z; As[base + 3] = t.w;
  }
  __syncthreads();
  int tr = tid >> 3, tc = tid & 7;
  int ra = tr * 4;
  float acc[4][8];
#pragma unroll
  for (int i = 0; i < 4; i++)
#pragma unroll
    for (int j = 0; j < 8; j++) acc[i][j] = 0.f;
#pragma unroll 4
  for (int k = 0; k < 64; k++) {
    float av[4];
#pragma unroll
    for (int i = 0; i < 4; i++) av[i] = As[(ra + i) * 68 + k];
    const float* wk = &Ws[k * 68 + tc * 8];
    float4 w0 = *(const float4*)wk;
    float4 w1 = *(const float4*)(wk + 4);
    float wv[8] = {w0.x, w0.y, w0.z, w0.w, w1.x, w1.y, w1.z, w1.w};
#pragma unroll
    for (int i = 0; i < 4; i++)
#pragma unroll
      for (int j = 0; j < 8; j++) acc[i][j] += av[i] * wv[j];
  }
#pragma unroll
  for (int i = 0; i < 4; i++) {
    int rn = n0 + ra + i;
    if (rn < N) {
      float* zr = zout + (size_t)rn * 64 + tc * 8;
      *(float4*)zr = make_float4(acc[i][0], acc[i][1], acc[i][2], acc[i][3]);
      *(float4*)(zr + 4) = make_float4(acc[i][4], acc[i][5], acc[i][6], acc[i][7]);
    }
  }
  float cs[8], cq[8];
#pragma unroll
  for (int j = 0; j < 8; j++) {
    float s = 0.f, q = 0.f;
#pragma unroll
    for (int i = 0; i < 4; i++) {
      s += acc[i][j];
      q += acc[i][j] * acc[i][j];
    }
    cs[j] = s;
    cq[j] = q;
  }
#pragma unroll
  for (int m = 8; m <= 32; m <<= 1) {
#pragma unroll
    for (int j = 0; j < 8; j++) {
      cs[j] += __shfl_xor(cs[j], m);
      cq[j] += __shfl_xor(cq[j], m);
    }
  }
  __syncthreads();  // Ws reusable
  int w = tid >> 6;
  if ((tid & 63) < 8) {
    int c = tc * 8;
#pragma unroll
    for (int j = 0; j < 8; j++) {
      Ws[w * 128 + c + j] = cs[j];
      Ws[w * 128 + 64 + c + j] = cq[j];
    }
  }
  __syncthreads();
  if (tid < 64) {
    float a = Ws[tid] + Ws[128 + tid] + Ws[256 + tid] + Ws[384 + tid];
    float b = Ws[64 + tid] + Ws[192 + tid] + Ws[320 + tid] + Ws[448 + tid];
    atomicAdd(&stats_out[tid], a);
    atomicAdd(&stats_out[64 + tid], b);
  }
}

// logits[n] = x[n] @ fcW0 + sum_l fcb[l]; also emits x16 (bf16 shadow of x)
__global__ __launch_bounds__(256) void k_head_init(
    const float* __restrict__ x, const float* __restrict__ fcW0,
    const float* __restrict__ fcb, float* __restrict__ logits,
    unsigned short* __restrict__ x16, int N) {
  __shared__ float vs[256 * 17];
  int tid = threadIdx.x;
  int n0 = blockIdx.x * 256;
  int n = n0 + tid;
  float acc[10];
#pragma unroll
  for (int c = 0; c < 10; c++) acc[c] = 0.f;
#pragma unroll 1
  for (int fb = 0; fb < 64; fb += 16) {
    __syncthreads();
#pragma unroll
    for (int g = 0; g < 4; g++) {
      int r = g * 64 + (tid >> 2);
      int q = tid & 3;
      int rn = n0 + r;
      float4 t = make_float4(0.f, 0.f, 0.f, 0.f);
      if (rn < N) {
        t = *(const float4*)(x + (size_t)rn * 64 + fb + 4 * q);
        *(ushort4*)(x16 + (size_t)rn * 64 + fb + 4 * q) =
            make_ushort4(f2bf(t.x), f2bf(t.y), f2bf(t.z), f2bf(t.w));
      }
      int base = r * 17 + 4 * q;
      vs[base] = t.x;
      vs[base + 1] = t.y;
      vs[base + 2] = t.z;
      vs[base + 3] = t.w;
    }
    __syncthreads();
    for (int fc = 0; fc < 16; fc++) {
      int f = fb + fc;
      float vf = vs[tid * 17 + fc];
      const float* wr = fcW0 + f * 10;
#pragma unroll
      for (int c = 0; c < 10; c++) acc[c] += vf * wr[c];
    }
  }
  if (n < N) {
    float* lr = logits + (size_t)n * 10;
#pragma unroll
    for (int c = 0; c < 10; c++)
      lr[c] = acc[c] + (fcb[c] + fcb[10 + c] + fcb[20 + c] + fcb[30 + c]);
  }
}

// h = relu(z*A+B) with AB from stats prologue; store h + h16; logits += h@fcWl.
// dofinal: skip h/h16 stores, finish logits and write log_softmax to out.
__global__ __launch_bounds__(256) void k_bn_head(
    const float* __restrict__ z,
    const float* __restrict__ stats_in, const float* __restrict__ gv,
    const float* __restrict__ bev,
    float* __restrict__ hout, unsigned short* __restrict__ h16out,
    const float* __restrict__ fcWl, float* __restrict__ logits,
    float* __restrict__ out, int dofinal, int N) {
  __shared__ float vs[256 * 17];
  __shared__ float ABs[128];
  int tid = threadIdx.x;
  if (tid < 64) {
    float inv_n = 1.f / (float)N;
    float mu = stats_in[tid] * inv_n;
    float var = stats_in[64 + tid] * inv_n - mu * mu;
    float A = rsqrtf(var + BN_EPS) * gv[tid];
    ABs[tid] = A;
    ABs[64 + tid] = bev[tid] - mu * A;
  }
  int n0 = blockIdx.x * 256;
  int n = n0 + tid;
  float acc[10];
#pragma unroll
  for (int c = 0; c < 10; c++) acc[c] = 0.f;
#pragma unroll 1
  for (int fb = 0; fb < 64; fb += 16) {
    __syncthreads();
#pragma unroll
    for (int g = 0; g < 4; g++) {
      int r = g * 64 + (tid >> 2);
      int q = tid & 3;
      int rn = n0 + r;
      float4 t = (rn < N) ? *(const float4*)(z + (size_t)rn * 64 + fb + 4 * q)
                          : make_float4(0.f, 0.f, 0.f, 0.f);
      int base = r * 17 + 4 * q;
      vs[base] = t.x;
      vs[base + 1] = t.y;
      vs[base + 2] = t.z;
      vs[base + 3] = t.w;
    }
    __syncthreads();
    float tl[16];
#pragma unroll
    for (int fc = 0; fc < 16; fc++) {
      int f = fb + fc;
      float val = vs[tid * 17 + fc] * ABs[f] + ABs[64 + f];
      tl[fc] = fmaxf(val, 0.f);
      const float* wr = fcWl + f * 10;
#pragma unroll
      for (int c = 0; c < 10; c++) acc[c] += tl[fc] * wr[c];
    }
    if (!dofinal) {
      __syncthreads();
#pragma unroll
      for (int fc = 0; fc < 16; fc++) vs[tid * 17 + fc] = tl[fc];
      __syncthreads();
#pragma unroll
      for (int g = 0; g < 4; g++) {  // coalesced h + h16 store via LDS bounce
        int r = g * 64 + (tid >> 2);
        int q = tid & 3;
        int rn = n0 + r;
        if (rn < N) {
          int base = r * 17 + 4 * q;
          float4 t = make_float4(vs[base], vs[base + 1], vs[base + 2], vs[base + 3]);
          *(float4*)(hout + (size_t)rn * 64 + fb + 4 * q) = t;
          *(ushort4*)(h16out + (size_t)rn * 64 + fb + 4 * q) =
              make_ushort4(f2bf(t.x), f2bf(t.y), f2bf(t.z), f2bf(t.w));
        }
      }
    }
  }
  if (n < N) {
    float* lr = logits + (size_t)n * 10;
    if (!dofinal) {
#pragma unroll
      for (int c = 0; c < 10; c++) lr[c] += acc[c];
    } else {
      float v[10];
      float m = -INFINITY;
#pragma unroll
      for (int c = 0; c < 10; c++) {
        v[c] = lr[c] + acc[c];
        m = fmaxf(m, v[c]);
      }
      float s = 0.f;
#pragma unroll
      for (int c = 0; c < 10; c++) s += expf(v[c] - m);
      float l = logf(s) + m;
      float* orow = out + (size_t)n * 10;
#pragma unroll
      for (int c = 0; c < 10; c++) orow[c] = v[c] - l;
    }
  }
}

extern "C" void kernel_launch(void* const* d_in, const int* in_sizes, int n_in,
                              void* d_out, int out_size, void* d_ws, size_t ws_size,
                              hipStream_t stream) {
  const float* x = (const float*)d_in[0];
  const int* ei = (const int*)d_in[1];
  const float* W1 = (const float*)d_in[2];
  const float* g1 = (const float*)d_in[4];
  const float* be1 = (const float*)d_in[5];
  const float* W2 = (const float*)d_in[6];
  const float* gbn = (const float*)d_in[8];
  const float* bbn = (const float*)d_in[9];
  const float* fcW = (const float*)d_in[10];
  const float* fcb = (const float*)d_in[11];
  float* out = (float*)d_out;

  const int N = in_sizes[0] / 64;
  const int E = in_sizes[1] / 2;
  const int* src = ei;
  const int* dst = ei + E;

  char* ws = (char*)d_ws;
  size_t off = 0;
  auto alloc = [&](size_t bytes) -> void* {
    void* p = ws + off;
    off = (off + bytes + 255) & ~(size_t)255;
    return p;
  };
  // zero-initialized region (single memset): counts + bcnt + stats
  int* counts = (int*)alloc((size_t)N * 4);
  int* bcnt = (int*)alloc(NBKT * 4);
  float* stats = (float*)alloc(6 * 128 * 4);
  size_t zspan = off;  // memset [ws, ws+zspan)
  int* bcur = (int*)alloc(NBKT * 4);
  int* offs = (int*)alloc((size_t)(N + 1) * 4);
  int* cursor = (int*)alloc((size_t)N * 4);
  int* csr = (int*)alloc((size_t)E * 4);
  float* hbuf = (float*)alloc((size_t)N * 64 * 4);
  float* zbuf = (float*)alloc((size_t)N * 64 * 4);
  float* vbuf = (float*)alloc((size_t)N * 64 * 4);
  float* logits = (float*)alloc((size_t)N * 10 * 4);
  int* blocksums = (int*)alloc(256 * 4);
  unsigned short* x16 = (unsigned short*)alloc((size_t)N * 64 * 2);
  unsigned short* h16 = (unsigned short*)alloc((size_t)N * 64 * 2);
  int2* ep = (int2*)vbuf;  // alias: ep dead before k_agg writes vbuf
  (void)ws_size;
  (void)n_in;
  (void)out_size;

  hipMemsetAsync(ws, 0, zspan, stream);
  int eb = (E + 255) / 256;
  int nb = (N + 255) / 256;
  int gb = (N + 127) / 128;
  int nscan = (N + SCAN_CHUNK - 1) / SCAN_CHUNK;  // <=256
  int nparts = (E + PCHUNK - 1) / PCHUNK;
  k_buckethist<<<512, 256, 0, stream>>>(dst, bcnt, E);
  k_scanblock<<<1, 256, 0, stream>>>(bcnt, bcur, NBKT);
  k_partition<<<nparts, 256, 0, stream>>>(src, dst, bcur, ep, E);
  k_hist2<<<eb, 256, 0, stream>>>(ep, counts, E);
  k_blocksum<<<nscan, 256, 0, stream>>>(counts, blocksums, N);
  k_scanfinal2<<<nscan, 256, 0, stream>>>(counts, blocksums, nscan, offs, cursor, N);
  k_scatter2<<<eb, 256, 0, stream>>>(ep, cursor, csr, E);
  k_head_init<<<nb, 256, 0, stream>>>(x, fcW, fcb, logits, x16, N);

  const float* hin = x;
  const unsigned short* hin16 = x16;
  for (int l = 0; l < 3; l++) {
    float* st1 = stats + (2 * l) * 128;
    float* st2 = stats + (2 * l + 1) * 128;
    k_agg<<<(N * 64 + 255) / 256, 256, 0, stream>>>(hin, hin16, offs, csr, vbuf, N);
    k_gemm2<<<gb, 256, 0, stream>>>(vbuf, zbuf, W1 + l * 4096, nullptr, nullptr,
                                    nullptr, 0, st1, N);
    k_gemm2<<<gb, 256, 0, stream>>>(zbuf, zbuf, W2 + l * 4096, st1, g1 + l * 64,
                                    be1 + l * 64, 1, st2, N);
    int dofinal = (l == 2) ? 1 : 0;
    k_bn_head<<<nb, 256, 0, stream>>>(zbuf, st2, gbn + l * 64, bbn + l * 64, hbuf,
                                      h16, fcW + (l + 1) * 640, logits, out,
                                      dofinal, N);
    hin = hbuf;
    hin16 = h16;
  }
}

// Round 7
// 583.351 us; speedup vs baseline: 1.7915x; 1.1332x over previous
//
#include <hip/hip_runtime.h>
#include <math.h>

// GIN: N=100000 nodes, E=1600000 edges, F=D=64, L=3 layers, C=10 classes.
// R7: launch-count 21->16 (gaps ~12us each were the top cost).
//   - CSR tail (hist2/blocksum/scanfinal2/scatter2) replaced by one
//     bucket-local LDS counting-sort kernel (k_bucketsort).
//   - memset dispatch removed: buckethist writes per-block partials; the
//     1-block scan sums them and zeros stats.
//   - head_init merged into the partition dispatch (independent blocks).
//   - k_agg: 16-deep gather batch (mean degree 16).

#define BN_EPS 1e-5f
#define NBKT 256     // dst buckets (dst>>9)
#define PCHUNK 8192  // edges per partition block
#define HBLK 128     // buckethist blocks

__device__ __forceinline__ float bf2f(unsigned short u) {
  return __uint_as_float(((unsigned int)u) << 16);
}
__device__ __forceinline__ unsigned short f2bf(float x) {  // RNE
  unsigned int b = __float_as_uint(x);
  return (unsigned short)((b + 0x7FFFu + ((b >> 16) & 1u)) >> 16);
}

// ---------- CSR build ----------

// per-block bucket histogram partials (no global pre-zero needed)
__global__ __launch_bounds__(256) void k_buckethist(const int* __restrict__ dst,
                                                    int* __restrict__ bpart, int E) {
  __shared__ int lh[NBKT];
  lh[threadIdx.x] = 0;
  __syncthreads();
  for (int e = blockIdx.x * 256 + threadIdx.x; e < E; e += HBLK * 256)
    atomicAdd(&lh[dst[e] >> 9], 1);
  __syncthreads();
  bpart[blockIdx.x * NBKT + threadIdx.x] = lh[threadIdx.x];
}

// 1 block: sum partials -> exclusive bucket scan -> bbase/bcur; zero stats
__global__ __launch_bounds__(256) void k_scanblock2(const int* __restrict__ bpart,
                                                    int* __restrict__ bbase,
                                                    int* __restrict__ bcur,
                                                    float* __restrict__ stats, int E) {
  __shared__ int ts[256];
  int t = threadIdx.x;
  int s = 0;
  for (int i = 0; i < HBLK; i++) s += bpart[i * NBKT + t];
  ts[t] = s;
  __syncthreads();
  for (int o = 1; o < 256; o <<= 1) {
    int add = (t >= o) ? ts[t - o] : 0;
    __syncthreads();
    ts[t] += add;
    __syncthreads();
  }
  int excl = ts[t] - s;
  bbase[t] = excl;
  bcur[t] = excl;
  if (t == 255) bbase[256] = ts[255];  // == E
  stats[t] = 0.f;
  stats[256 + t] = 0.f;
  stats[512 + t] = 0.f;
}

// combined dispatch: blocks [0,nparts) partition edges into dst-buckets;
// blocks [nparts,..) do head_init: logits = x@fcW0 + sum_l fcb[l], emit x16.
__global__ __launch_bounds__(256) void k_part_head(
    const int* __restrict__ src, const int* __restrict__ dst,
    int* __restrict__ bcur, int2* __restrict__ ep, int E, int nparts,
    const float* __restrict__ x, const float* __restrict__ fcW0,
    const float* __restrict__ fcb, float* __restrict__ logits,
    unsigned short* __restrict__ x16, int N) {
  __shared__ char smem[256 * 17 * 4];
  int tid = threadIdx.x;
  if ((int)blockIdx.x < nparts) {
    int* lh = (int*)smem;
    int* lbase = lh + NBKT;
    int* lcur = lh + 2 * NBKT;
    int base = blockIdx.x * PCHUNK;
    int end = min(base + PCHUNK, E);
    lh[tid] = 0;
    lcur[tid] = 0;
    __syncthreads();
    for (int e = base + tid; e < end; e += 256) atomicAdd(&lh[dst[e] >> 9], 1);
    __syncthreads();
    int c = lh[tid];
    lbase[tid] = c ? atomicAdd(&bcur[tid], c) : 0;
    __syncthreads();
    for (int e = base + tid; e < end; e += 256) {
      int d = dst[e];
      int b = d >> 9;
      int r = atomicAdd(&lcur[b], 1);
      ep[lbase[b] + r] = make_int2(src[e], d);
    }
  } else {
    float* vs = (float*)smem;
    int n0 = (blockIdx.x - nparts) * 256;
    int n = n0 + tid;
    float acc[10];
#pragma unroll
    for (int c = 0; c < 10; c++) acc[c] = 0.f;
#pragma unroll 1
    for (int fb = 0; fb < 64; fb += 16) {
      __syncthreads();
#pragma unroll
      for (int g = 0; g < 4; g++) {
        int r = g * 64 + (tid >> 2);
        int q = tid & 3;
        int rn = n0 + r;
        float4 t = make_float4(0.f, 0.f, 0.f, 0.f);
        if (rn < N) {
          t = *(const float4*)(x + (size_t)rn * 64 + fb + 4 * q);
          *(ushort4*)(x16 + (size_t)rn * 64 + fb + 4 * q) =
              make_ushort4(f2bf(t.x), f2bf(t.y), f2bf(t.z), f2bf(t.w));
        }
        int base = r * 17 + 4 * q;
        vs[base] = t.x;
        vs[base + 1] = t.y;
        vs[base + 2] = t.z;
        vs[base + 3] = t.w;
      }
      __syncthreads();
      for (int fc = 0; fc < 16; fc++) {
        int f = fb + fc;
        float vf = vs[tid * 17 + fc];
        const float* wr = fcW0 + f * 10;
#pragma unroll
        for (int c = 0; c < 10; c++) acc[c] += vf * wr[c];
      }
    }
    if (n < N) {
      float* lr = logits + (size_t)n * 10;
#pragma unroll
      for (int c = 0; c < 10; c++)
        lr[c] = acc[c] + (fcb[c] + fcb[10 + c] + fcb[20 + c] + fcb[30 + c]);
    }
  }
}

// per-bucket LDS counting sort: emits offs (node CSR offsets) and csr.
// Bucket b covers nodes [b*512,(b+1)*512); its edges are ep[bbase[b],bbase[b+1]).
__global__ __launch_bounds__(256) void k_bucketsort(
    const int2* __restrict__ ep, const int* __restrict__ bbase,
    int* __restrict__ offs, int* __restrict__ csr) {
  __shared__ int cnt[512];
  __shared__ int ts[256];
  __shared__ int cur[512];
  int t = threadIdx.x;
  int b = blockIdx.x;
  int lo = bbase[b], hi = bbase[b + 1];
  cnt[t] = 0;
  cnt[t + 256] = 0;
  __syncthreads();
  for (int e = lo + t; e < hi; e += 256) atomicAdd(&cnt[ep[e].y & 511], 1);
  __syncthreads();
  int c0 = cnt[2 * t], c1 = cnt[2 * t + 1];
  int s = c0 + c1;
  ts[t] = s;
  __syncthreads();
  for (int o = 1; o < 256; o <<= 1) {
    int add = (t >= o) ? ts[t - o] : 0;
    __syncthreads();
    ts[t] += add;
    __syncthreads();
  }
  int excl = ts[t] - s;
  cur[2 * t] = excl;
  cur[2 * t + 1] = excl + c0;
  int n0 = b * 512;
  offs[n0 + 2 * t] = lo + excl;          // nodes >= N get offs == E; harmless
  offs[n0 + 2 * t + 1] = lo + excl + c0; // (offs array sized NBKT*512+1)
  __syncthreads();
  for (int e = lo + t; e < hi; e += 256) {
    int2 p = ep[e];
    int pos = atomicAdd(&cur[p.y & 511], 1);
    csr[lo + pos] = p.x;
  }
}

// ---------- compute ----------

// wave-per-node aggregation: v[n] = h[n] (fp32) + sum_{e} bf16(h[src_e])
__global__ __launch_bounds__(256) void k_agg(
    const float* __restrict__ h, const unsigned short* __restrict__ h16,
    const int* __restrict__ offs, const int* __restrict__ csr,
    float* __restrict__ vout, int N) {
  int gid = blockIdx.x * blockDim.x + threadIdx.x;
  int wid = __builtin_amdgcn_readfirstlane(gid >> 6);  // node id, wave-uniform
  int lane = threadIdx.x & 63;
  if (wid >= N) return;
  int e0 = offs[wid];
  int e1 = offs[wid + 1];
  float acc = h[(size_t)wid * 64 + lane];
  int e = e0;
  for (; e + 16 <= e1; e += 16) {  // 16 gathers in flight (mean degree 16)
    int s0 = csr[e], s1 = csr[e + 1], s2 = csr[e + 2], s3 = csr[e + 3];
    int s4 = csr[e + 4], s5 = csr[e + 5], s6 = csr[e + 6], s7 = csr[e + 7];
    int s8 = csr[e + 8], s9 = csr[e + 9], sa = csr[e + 10], sb = csr[e + 11];
    int sc = csr[e + 12], sd = csr[e + 13], se = csr[e + 14], sf = csr[e + 15];
    float a0 = bf2f(h16[(size_t)s0 * 64 + lane]);
    float a1 = bf2f(h16[(size_t)s1 * 64 + lane]);
    float a2 = bf2f(h16[(size_t)s2 * 64 + lane]);
    float a3 = bf2f(h16[(size_t)s3 * 64 + lane]);
    float a4 = bf2f(h16[(size_t)s4 * 64 + lane]);
    float a5 = bf2f(h16[(size_t)s5 * 64 + lane]);
    float a6 = bf2f(h16[(size_t)s6 * 64 + lane]);
    float a7 = bf2f(h16[(size_t)s7 * 64 + lane]);
    float a8 = bf2f(h16[(size_t)s8 * 64 + lane]);
    float a9 = bf2f(h16[(size_t)s9 * 64 + lane]);
    float aa = bf2f(h16[(size_t)sa * 64 + lane]);
    float ab = bf2f(h16[(size_t)sb * 64 + lane]);
    float ac = bf2f(h16[(size_t)sc * 64 + lane]);
    float ad = bf2f(h16[(size_t)sd * 64 + lane]);
    float ae = bf2f(h16[(size_t)se * 64 + lane]);
    float af = bf2f(h16[(size_t)sf * 64 + lane]);
    acc += (((a0 + a1) + (a2 + a3)) + ((a4 + a5) + (a6 + a7))) +
           (((a8 + a9) + (aa + ab)) + ((ac + ad) + (ae + af)));
  }
  for (; e + 4 <= e1; e += 4) {
    int s0 = csr[e], s1 = csr[e + 1], s2 = csr[e + 2], s3 = csr[e + 3];
    float a0 = bf2f(h16[(size_t)s0 * 64 + lane]);
    float a1 = bf2f(h16[(size_t)s1 * 64 + lane]);
    float a2 = bf2f(h16[(size_t)s2 * 64 + lane]);
    float a3 = bf2f(h16[(size_t)s3 * 64 + lane]);
    acc += (a0 + a1) + (a2 + a3);
  }
  for (; e < e1; e++) acc += bf2f(h16[(size_t)csr[e] * 64 + lane]);
  vout[(size_t)wid * 64 + lane] = acc;
}

// LDS-tiled GEMM, 128 rows/block, 4x8 thread tile.
//  dobn=1: AB computed in prologue from stats_in/gv/bev; BN+ReLU on A staging.
// Epilogue: column sum/sumsq -> atomicAdd stats_out[128]. In-place safe.
__global__ __launch_bounds__(256) void k_gemm2(
    const float* __restrict__ vin, float* __restrict__ zout,
    const float* __restrict__ W,
    const float* __restrict__ stats_in, const float* __restrict__ gv,
    const float* __restrict__ bev, int dobn,
    float* __restrict__ stats_out, int N) {
  __shared__ float As[128 * 68];
  __shared__ float Ws[64 * 68];
  __shared__ float ABs[128];
  int tid = threadIdx.x;
  int n0 = blockIdx.x * 128;
  if (dobn) {
    if (tid < 64) {
      float inv_n = 1.f / (float)N;
      float mu = stats_in[tid] * inv_n;
      float var = stats_in[64 + tid] * inv_n - mu * mu;
      float A = rsqrtf(var + BN_EPS) * gv[tid];
      ABs[tid] = A;
      ABs[64 + tid] = bev[tid] - mu * A;
    }
    __syncthreads();
  }
#pragma unroll
  for (int i = 0; i < 4; i++) {  // stage W (64x64)
    int g = tid + i * 256;
    int r = g >> 4, q = g & 15;
    float4 t = *(const float4*)(W + r * 64 + 4 * q);
    int base = r * 68 + 4 * q;
    Ws[base] = t.x; Ws[base + 1] = t.y; Ws[base + 2] = t.z; Ws[base + 3] = t.w;
  }
#pragma unroll
  for (int i = 0; i < 8; i++) {  // stage A (128x64), optional BN+ReLU
    int g = tid + i * 256;
    int r = g >> 4, q = g & 15;
    int rn = n0 + r;
    float4 t = make_float4(0.f, 0.f, 0.f, 0.f);
    if (rn < N) t = *(const float4*)(vin + (size_t)rn * 64 + 4 * q);
    if (dobn) {
      float4 a = *(const float4*)(ABs + 4 * q);
      float4 b = *(const float4*)(ABs + 64 + 4 * q);
      t.x = fmaxf(t.x * a.x + b.x, 0.f);
      t.y = fmaxf(t.y * a.y + b.y, 0.f);
      t.z = fmaxf(t.z * a.z + b.z, 0.f);
      t.w = fmaxf(t.w * a.w + b.w, 0.f);
    }
    int base = r * 68 + 4 * q;
    As[base] = t.x; As[base + 1] = t.y; As[base + 2] = t.z; As[base + 3] = t.w;
  }
  __syncthreads();
  int tr = tid >> 3, tc = tid & 7;
  int ra = tr * 4;
  float acc[4][8];
#pragma unroll
  for (int i = 0; i < 4; i++)
#pragma unroll
    for (int j = 0; j < 8; j++) acc[i][j] = 0.f;
#pragma unroll 4
  for (int k = 0; k < 64; k++) {
    float av[4];
#pragma unroll
    for (int i = 0; i < 4; i++) av[i] = As[(ra + i) * 68 + k];
    const float* wk = &Ws[k * 68 + tc * 8];
    float4 w0 = *(const float4*)wk;
    float4 w1 = *(const float4*)(wk + 4);
    float wv[8] = {w0.x, w0.y, w0.z, w0.w, w1.x, w1.y, w1.z, w1.w};
#pragma unroll
    for (int i = 0; i < 4; i++)
#pragma unroll
      for (int j = 0; j < 8; j++) acc[i][j] += av[i] * wv[j];
  }
#pragma unroll
  for (int i = 0; i < 4; i++) {
    int rn = n0 + ra + i;
    if (rn < N) {
      float* zr = zout + (size_t)rn * 64 + tc * 8;
      *(float4*)zr = make_float4(acc[i][0], acc[i][1], acc[i][2], acc[i][3]);
      *(float4*)(zr + 4) = make_float4(acc[i][4], acc[i][5], acc[i][6], acc[i][7]);
    }
  }
  float cs[8], cq[8];
#pragma unroll
  for (int j = 0; j < 8; j++) {
    float s = 0.f, q = 0.f;
#pragma unroll
    for (int i = 0; i < 4; i++) {
      s += acc[i][j];
      q += acc[i][j] * acc[i][j];
    }
    cs[j] = s;
    cq[j] = q;
  }
#pragma unroll
  for (int m = 8; m <= 32; m <<= 1) {
#pragma unroll
    for (int j = 0; j < 8; j++) {
      cs[j] += __shfl_xor(cs[j], m);
      cq[j] += __shfl_xor(cq[j], m);
    }
  }
  __syncthreads();  // Ws reusable
  int w = tid >> 6;
  if ((tid & 63) < 8) {
    int c = tc * 8;
#pragma unroll
    for (int j = 0; j < 8; j++) {
      Ws[w * 128 + c + j] = cs[j];
      Ws[w * 128 + 64 + c + j] = cq[j];
    }
  }
  __syncthreads();
  if (tid < 64) {
    float a = Ws[tid] + Ws[128 + tid] + Ws[256 + tid] + Ws[384 + tid];
    float b = Ws[64 + tid] + Ws[192 + tid] + Ws[320 + tid] + Ws[448 + tid];
    atomicAdd(&stats_out[tid], a);
    atomicAdd(&stats_out[64 + tid], b);
  }
}

// h = relu(z*A+B) with AB from stats prologue; store h + h16; logits += h@fcWl.
// dofinal: skip h/h16 stores, finish logits and write log_softmax to out.
__global__ __launch_bounds__(256) void k_bn_head(
    const float* __restrict__ z,
    const float* __restrict__ stats_in, const float* __restrict__ gv,
    const float* __restrict__ bev,
    float* __restrict__ hout, unsigned short* __restrict__ h16out,
    const float* __restrict__ fcWl, float* __restrict__ logits,
    float* __restrict__ out, int dofinal, int N) {
  __shared__ float vs[256 * 17];
  __shared__ float ABs[128];
  int tid = threadIdx.x;
  if (tid < 64) {
    float inv_n = 1.f / (float)N;
    float mu = stats_in[tid] * inv_n;
    float var = stats_in[64 + tid] * inv_n - mu * mu;
    float A = rsqrtf(var + BN_EPS) * gv[tid];
    ABs[tid] = A;
    ABs[64 + tid] = bev[tid] - mu * A;
  }
  int n0 = blockIdx.x * 256;
  int n = n0 + tid;
  float acc[10];
#pragma unroll
  for (int c = 0; c < 10; c++) acc[c] = 0.f;
#pragma unroll 1
  for (int fb = 0; fb < 64; fb += 16) {
    __syncthreads();
#pragma unroll
    for (int g = 0; g < 4; g++) {
      int r = g * 64 + (tid >> 2);
      int q = tid & 3;
      int rn = n0 + r;
      float4 t = (rn < N) ? *(const float4*)(z + (size_t)rn * 64 + fb + 4 * q)
                          : make_float4(0.f, 0.f, 0.f, 0.f);
      int base = r * 17 + 4 * q;
      vs[base] = t.x;
      vs[base + 1] = t.y;
      vs[base + 2] = t.z;
      vs[base + 3] = t.w;
    }
    __syncthreads();
    float tl[16];
#pragma unroll
    for (int fc = 0; fc < 16; fc++) {
      int f = fb + fc;
      float val = vs[tid * 17 + fc] * ABs[f] + ABs[64 + f];
      tl[fc] = fmaxf(val, 0.f);
      const float* wr = fcWl + f * 10;
#pragma unroll
      for (int c = 0; c < 10; c++) acc[c] += tl[fc] * wr[c];
    }
    if (!dofinal) {
      __syncthreads();
#pragma unroll
      for (int fc = 0; fc < 16; fc++) vs[tid * 17 + fc] = tl[fc];
      __syncthreads();
#pragma unroll
      for (int g = 0; g < 4; g++) {  // coalesced h + h16 store via LDS bounce
        int r = g * 64 + (tid >> 2);
        int q = tid & 3;
        int rn = n0 + r;
        if (rn < N) {
          int base = r * 17 + 4 * q;
          float4 t = make_float4(vs[base], vs[base + 1], vs[base + 2], vs[base + 3]);
          *(float4*)(hout + (size_t)rn * 64 + fb + 4 * q) = t;
          *(ushort4*)(h16out + (size_t)rn * 64 + fb + 4 * q) =
              make_ushort4(f2bf(t.x), f2bf(t.y), f2bf(t.z), f2bf(t.w));
        }
      }
    }
  }
  if (n < N) {
    float* lr = logits + (size_t)n * 10;
    if (!dofinal) {
#pragma unroll
      for (int c = 0; c < 10; c++) lr[c] += acc[c];
    } else {
      float v[10];
      float m = -INFINITY;
#pragma unroll
      for (int c = 0; c < 10; c++) {
        v[c] = lr[c] + acc[c];
        m = fmaxf(m, v[c]);
      }
      float s = 0.f;
#pragma unroll
      for (int c = 0; c < 10; c++) s += expf(v[c] - m);
      float l = logf(s) + m;
      float* orow = out + (size_t)n * 10;
#pragma unroll
      for (int c = 0; c < 10; c++) orow[c] = v[c] - l;
    }
  }
}

extern "C" void kernel_launch(void* const* d_in, const int* in_sizes, int n_in,
                              void* d_out, int out_size, void* d_ws, size_t ws_size,
                              hipStream_t stream) {
  const float* x = (const float*)d_in[0];
  const int* ei = (const int*)d_in[1];
  const float* W1 = (const float*)d_in[2];
  const float* g1 = (const float*)d_in[4];
  const float* be1 = (const float*)d_in[5];
  const float* W2 = (const float*)d_in[6];
  const float* gbn = (const float*)d_in[8];
  const float* bbn = (const float*)d_in[9];
  const float* fcW = (const float*)d_in[10];
  const float* fcb = (const float*)d_in[11];
  float* out = (float*)d_out;

  const int N = in_sizes[0] / 64;
  const int E = in_sizes[1] / 2;
  const int* src = ei;
  const int* dst = ei + E;

  char* ws = (char*)d_ws;
  size_t off = 0;
  auto alloc = [&](size_t bytes) -> void* {
    void* p = ws + off;
    off = (off + bytes + 255) & ~(size_t)255;
    return p;
  };
  float* stats = (float*)alloc(6 * 128 * 4);     // zeroed by k_scanblock2
  int* bpart = (int*)alloc((size_t)HBLK * NBKT * 4);
  int* bbase = (int*)alloc((NBKT + 1) * 4);
  int* bcur = (int*)alloc(NBKT * 4);
  int* offs = (int*)alloc(((size_t)NBKT * 512 + 1) * 4);
  int* csr = (int*)alloc((size_t)E * 4);
  float* hbuf = (float*)alloc((size_t)N * 64 * 4);
  float* zbuf = (float*)alloc((size_t)N * 64 * 4);
  float* vbuf = (float*)alloc((size_t)N * 64 * 4);
  float* logits = (float*)alloc((size_t)N * 10 * 4);
  unsigned short* x16 = (unsigned short*)alloc((size_t)N * 64 * 2);
  unsigned short* h16 = (unsigned short*)alloc((size_t)N * 64 * 2);
  int2* ep = (int2*)vbuf;  // alias: ep dead before k_agg writes vbuf
  (void)ws_size;
  (void)n_in;
  (void)out_size;

  int nb = (N + 255) / 256;
  int gb = (N + 127) / 128;
  int nparts = (E + PCHUNK - 1) / PCHUNK;
  k_buckethist<<<HBLK, 256, 0, stream>>>(dst, bpart, E);
  k_scanblock2<<<1, 256, 0, stream>>>(bpart, bbase, bcur, stats, E);
  k_part_head<<<nparts + nb, 256, 0, stream>>>(src, dst, bcur, ep, E, nparts, x,
                                               fcW, fcb, logits, x16, N);
  k_bucketsort<<<NBKT, 256, 0, stream>>>(ep, bbase, offs, csr);

  const float* hin = x;
  const unsigned short* hin16 = x16;
  for (int l = 0; l < 3; l++) {
    float* st1 = stats + (2 * l) * 128;
    float* st2 = stats + (2 * l + 1) * 128;
    k_agg<<<(N * 64 + 255) / 256, 256, 0, stream>>>(hin, hin16, offs, csr, vbuf, N);
    k_gemm2<<<gb, 256, 0, stream>>>(vbuf, zbuf, W1 + l * 4096, nullptr, nullptr,
                                    nullptr, 0, st1, N);
    k_gemm2<<<gb, 256, 0, stream>>>(zbuf, zbuf, W2 + l * 4096, st1, g1 + l * 64,
                                    be1 + l * 64, 1, st2, N);
    int dofinal = (l == 2) ? 1 : 0;
    k_bn_head<<<nb, 256, 0, stream>>>(zbuf, st2, gbn + l * 64, bbn + l * 64, hbuf,
                                      h16, fcW + (l + 1) * 640, logits, out,
                                      dofinal, N);
    hin = hbuf;
    hin16 = h16;
  }
}